// Round 6
// baseline (264.454 us; speedup 1.0000x reference)
//
#include <hip/hip_runtime.h>
#include <hip/hip_bf16.h>

#define B_SZ 16384
#define F_SZ 2048
#define D_SZ 256
#define E_SZ 8
#define GRID_G 1040   // (sum_e ceil(count_e/32) <= 520) * 2 n-tiles

typedef __attribute__((ext_vector_type(8))) short bhalf8;
typedef __attribute__((ext_vector_type(4))) float fl4;

__device__ __forceinline__ short f2b(float f) {
  __hip_bfloat16 h = __float2bfloat16(f);
  union { __hip_bfloat16 h; short s; } u;
  u.h = h;
  return u.s;
}

// ---------------- bucket scatter ----------------
__global__ void k_scatter(const int* __restrict__ ids, int* __restrict__ counts,
                          int* __restrict__ perm) {
  __shared__ int lcnt[E_SZ], lbase[E_SZ];
  int t = threadIdx.x;
  if (t < E_SZ) lcnt[t] = 0;
  __syncthreads();
  int b = blockIdx.x * 256 + t;
  int e = ids[b];
  int p = atomicAdd(&lcnt[e], 1);
  __syncthreads();
  if (t < E_SZ) lbase[t] = atomicAdd(&counts[t], lcnt[t]);
  __syncthreads();
  perm[e * B_SZ + lbase[e] + p] = b;
}

// ---------------- W transpose+cast: Wt[e][d][f] = bf16(W[e][f][d]) ----------------
__global__ void k_transpose(const float* __restrict__ W, __hip_bfloat16* __restrict__ Wt) {
  __shared__ float tile[64][65];
  int e = blockIdx.z;
  int f0 = blockIdx.x * 64;
  int d0 = blockIdx.y * 64;
  int t = threadIdx.x;
  const float* src = W + ((size_t)e * F_SZ + f0) * D_SZ + d0;
  int fr = t >> 2, c0 = t & 3;
#pragma unroll
  for (int c = c0; c < 16; c += 4) {
    float4 v = *(const float4*)(src + (size_t)fr * D_SZ + c * 4);
    tile[fr][c * 4 + 0] = v.x;
    tile[fr][c * 4 + 1] = v.y;
    tile[fr][c * 4 + 2] = v.z;
    tile[fr][c * 4 + 3] = v.w;
  }
  __syncthreads();
  int dr = t >> 2, cc = t & 3;
  union { unsigned short u[16]; bhalf8 v[2]; } pk;
#pragma unroll
  for (int k = 0; k < 16; ++k) pk.u[k] = (unsigned short)f2b(tile[cc * 16 + k][dr]);
  __hip_bfloat16* dst = Wt + ((size_t)e * D_SZ + d0 + dr) * F_SZ + f0 + cc * 16;
  ((bhalf8*)dst)[0] = pk.v[0];
  ((bhalf8*)dst)[1] = pk.v[1];
}

// ---------------- async 16B global -> LDS ----------------
__device__ __forceinline__ void load_lds16(const __hip_bfloat16* g, __hip_bfloat16* l) {
  __builtin_amdgcn_global_load_lds((const __attribute__((address_space(1))) void*)g,
                                   (__attribute__((address_space(3))) void*)l, 16, 0, 0);
}

// ---------------- gather GEMM: BM=32, BN=128, BK=64 ----------------
// 4 waves 1x4 in n, wave tile 32x32; ~4 blocks/CU for 4-way latency overlap.
// LDS rows are 64 elems (8 x 16B chunks), chunk c stored at (c ^ (row&7)):
// fragment ds_read_b128 is 2-way aliased (free, m136), staging stays coalesced.
__launch_bounds__(256, 4)
__global__ void k_gemm(const float* __restrict__ x, const __hip_bfloat16* __restrict__ Wt,
                       const float* __restrict__ bias, const int* __restrict__ counts,
                       const int* __restrict__ perm, float* __restrict__ out) {
  // flattened decode: blockIdx.x -> (expert e, mbase, nb)
  int id = blockIdx.x;
  int nb = (id & 1) * 128;
  int mt = id >> 1;
  int e = -1, mbase = 0, count = 0;
  {
    int acc = 0;
#pragma unroll
    for (int ee = 0; ee < E_SZ; ++ee) {
      int c = counts[ee];
      int nt = (c + 31) >> 5;
      if (e < 0 && mt < acc + nt) { e = ee; mbase = (mt - acc) * 32; count = c; }
      acc += nt;
    }
  }
  if (e < 0) return;

  __shared__ __align__(16) __hip_bfloat16 As[32 * 64];    // 4 KB
  __shared__ __align__(16) __hip_bfloat16 Bs[128 * 64];   // 16 KB

  int t = threadIdx.x;
  int w = t >> 6;        // wave id: n-quadrant
  int lane = t & 63;
  int l15 = lane & 15;
  int q = lane >> 4;

  const int* permE = perm + e * B_SZ;

  // ---- A staging: flat float4 f = i*256+t -> row i*16+(t>>4), k=(t&15)*4 ----
  int tr = t >> 4;
  int tc = t & 15;
  const float* pA[2];
  int wAo[2];
#pragma unroll
  for (int i = 0; i < 2; ++i) {
    int r = i * 16 + tr;
    int gm = mbase + r;
    int src = permE[(gm < count) ? gm : mbase];
    pA[i] = x + (size_t)src * F_SZ + tc * 4;
    int cw = tc >> 1, half = tc & 1;
    wAo[i] = r * 64 + ((cw ^ (r & 7)) * 8) + half * 4;
  }

  // ---- B staging: physical chunk c = i*256+t; n=c>>3; logical chunk=(c&7)^(n&7) ----
  const __hip_bfloat16* pB[4];
  __hip_bfloat16* dstB[4];
#pragma unroll
  for (int i = 0; i < 4; ++i) {
    int c = i * 256 + t;
    int n = c >> 3;
    int cl = (c & 7) ^ (n & 7);
    pB[i] = Wt + (size_t)(e * D_SZ + nb + n) * F_SZ + cl * 8;
    dstB[i] = Bs + (size_t)(i * 256 + w * 64) * 8;   // wave-uniform base
  }

  // fragment read offsets (element units)
  int rAo[2][2], rBo[2][2];
#pragma unroll
  for (int ks = 0; ks < 2; ++ks) {
#pragma unroll
    for (int i = 0; i < 2; ++i) {
      int m = i * 16 + l15;
      rAo[ks][i] = m * 64 + (((ks * 4 + q) ^ (m & 7)) * 8);
    }
#pragma unroll
    for (int j = 0; j < 2; ++j) {
      int n = w * 32 + j * 16 + l15;
      rBo[ks][j] = n * 64 + (((ks * 4 + q) ^ (n & 7)) * 8);
    }
  }

  fl4 zz = {0.0f, 0.0f, 0.0f, 0.0f};
  fl4 acc[2][2];
#pragma unroll
  for (int i = 0; i < 2; ++i)
#pragma unroll
    for (int j = 0; j < 2; ++j) acc[i][j] = zz;

  for (int k0 = 0; k0 < F_SZ; k0 += 64) {
    __syncthreads();   // previous iter's fragment reads complete

    float4 av[2];
#pragma unroll
    for (int i = 0; i < 2; ++i) av[i] = *(const float4*)(pA[i] + k0);
#pragma unroll
    for (int i = 0; i < 4; ++i) load_lds16(pB[i] + k0, dstB[i]);
#pragma unroll
    for (int i = 0; i < 2; ++i) {
      short4 s;
      s.x = f2b(av[i].x); s.y = f2b(av[i].y);
      s.z = f2b(av[i].z); s.w = f2b(av[i].w);
      *(short4*)(As + wAo[i]) = s;
    }

    __syncthreads();   // staging complete

#pragma unroll
    for (int ks = 0; ks < 2; ++ks) {
      bhalf8 af[2], bf[2];
#pragma unroll
      for (int i = 0; i < 2; ++i) af[i] = *(const bhalf8*)(As + rAo[ks][i]);
#pragma unroll
      for (int j = 0; j < 2; ++j) bf[j] = *(const bhalf8*)(Bs + rBo[ks][j]);
#pragma unroll
      for (int i = 0; i < 2; ++i)
#pragma unroll
        for (int j = 0; j < 2; ++j)
          acc[i][j] = __builtin_amdgcn_mfma_f32_16x16x32_bf16(af[i], bf[j], acc[i][j], 0, 0, 0);
    }
  }

  // epilogue: C/D layout col = lane&15, row = q*4 + reg
  float bv[2];
#pragma unroll
  for (int j = 0; j < 2; ++j) bv[j] = bias[e * D_SZ + nb + w * 32 + j * 16 + l15];

#pragma unroll
  for (int i = 0; i < 2; ++i) {
#pragma unroll
    for (int r = 0; r < 4; ++r) {
      int gm = mbase + i * 16 + q * 4 + r;
      if (gm < count) {
        int row = permE[gm];
        float* po = out + (size_t)row * D_SZ + nb + w * 32;
#pragma unroll
        for (int j = 0; j < 2; ++j) po[j * 16 + l15] = acc[i][j][r] + bv[j];
      }
    }
  }
}

extern "C" void kernel_launch(void* const* d_in, const int* in_sizes, int n_in,
                              void* d_out, int out_size, void* d_ws, size_t ws_size,
                              hipStream_t stream) {
  const float* x = (const float*)d_in[0];
  const float* W = (const float*)d_in[1];
  const float* bias = (const float*)d_in[2];
  const int* ids = (const int*)d_in[3];
  float* out = (float*)d_out;

  char* ws = (char*)d_ws;
  int* counts = (int*)ws;                                 // 32 B
  int* perm = (int*)(ws + 256);                           // 512 KB
  __hip_bfloat16* Wt = (__hip_bfloat16*)(ws + (1 << 20)); // 8 MB

  hipMemsetAsync(counts, 0, E_SZ * sizeof(int), stream);
  k_scatter<<<B_SZ / 256, 256, 0, stream>>>(ids, counts, perm);
  k_transpose<<<dim3(F_SZ / 64, D_SZ / 64, E_SZ), 256, 0, stream>>>(W, Wt);
  k_gemm<<<GRID_G, 256, 0, stream>>>(x, Wt, bias, counts, perm, out);
}